// Round 1
// baseline (235.960 us; speedup 1.0000x reference)
//
#include <hip/hip_runtime.h>

#define EPS 1e-8f

__global__ __launch_bounds__(256) void gaussians_cov_kernel(
    const float4* __restrict__ quat,
    const float*  __restrict__ scale,
    float*        __restrict__ out,
    int n)
{
    int i = blockIdx.x * blockDim.x + threadIdx.x;
    if (i >= n) return;

    float4 q = quat[i];
    float w = q.x, x = q.y, y = q.z, z = q.w;

    // R entries are quadratic in normalized q: scale pairwise products by 2/|q|^2.
    float n2  = w*w + x*x + y*y + z*z;
    float t   = 2.0f / n2;

    float xx = x*x*t, yy = y*y*t, zz = z*z*t;
    float xy = x*y*t, xz = x*z*t, yz = y*z*t;
    float wx = w*x*t, wy = w*y*t, wz = w*z*t;

    float r00 = 1.0f - yy - zz, r01 = xy - wz,        r02 = xz + wy;
    float r10 = xy + wz,        r11 = 1.0f - xx - zz, r12 = yz - wx;
    float r20 = xz - wy,        r21 = yz + wx,        r22 = 1.0f - xx - yy;

    float s0 = fabsf(scale[3*i + 0]) + EPS;
    float s1 = fabsf(scale[3*i + 1]) + EPS;
    float s2 = fabsf(scale[3*i + 2]) + EPS;
    float a = s0*s0, b = s1*s1, c = s2*s2;

    // M = R * diag(s^2) * R^T (symmetric, 6 unique entries)
    float m00 = r00*r00*a + r01*r01*b + r02*r02*c;
    float m01 = r00*r10*a + r01*r11*b + r02*r12*c;
    float m02 = r00*r20*a + r01*r21*b + r02*r22*c;
    float m11 = r10*r10*a + r11*r11*b + r12*r12*c;
    float m12 = r10*r20*a + r11*r21*b + r12*r22*c;
    float m22 = r20*r20*a + r21*r21*b + r22*r22*c;

    float* o = out + 9*i;
    o[0] = m00; o[1] = m01; o[2] = m02;
    o[3] = m01; o[4] = m11; o[5] = m12;
    o[6] = m02; o[7] = m12; o[8] = m22;
}

extern "C" void kernel_launch(void* const* d_in, const int* in_sizes, int n_in,
                              void* d_out, int out_size, void* d_ws, size_t ws_size,
                              hipStream_t stream) {
    const float4* quat  = (const float4*)d_in[0];
    const float*  scale = (const float*)d_in[1];
    float* out = (float*)d_out;
    int n = in_sizes[0] / 4;   // quaternion is (N,4)

    int block = 256;
    int grid  = (n + block - 1) / block;
    gaussians_cov_kernel<<<grid, block, 0, stream>>>(quat, scale, out, n);
}

// Round 2
// 224.917 us; speedup vs baseline: 1.0491x; 1.0491x over previous
//
#include <hip/hip_runtime.h>

#define EPS 1e-8f
#define TILE 256   // gaussians per block == blockDim.x

__global__ __launch_bounds__(256) void gaussians_cov_kernel(
    const float4* __restrict__ quat,
    const float4* __restrict__ scale4,   // scale (N,3) viewed as float4 stream
    float4*       __restrict__ out4,     // out (N,9) viewed as float4 stream
    int n)
{
    __shared__ float s_scale[TILE * 3];  // 3 KB
    __shared__ float s_out[TILE * 9];    // 9 KB

    const int t    = threadIdx.x;
    const int base = blockIdx.x * TILE;

    // ---- cooperative coalesced load of the scale tile (192 float4 / block) ----
    {
        const int sbase4 = blockIdx.x * (TILE * 3 / 4);
        const int stot4  = (3 * n) / 4;          // total float4 in scale (3N divisible by 4 here)
        if (t < TILE * 3 / 4) {
            int gi = sbase4 + t;
            if (gi < stot4) ((float4*)s_scale)[t] = scale4[gi];
        }
    }
    __syncthreads();

    // ---- per-thread compute ----
    const int i = base + t;
    if (i < n) {
        float4 q = quat[i];                      // coalesced 16 B/lane
        float w = q.x, x = q.y, y = q.z, z = q.w;

        // R is quadratic in normalized q: fold normalization into t2 = 2/|q|^2 (no sqrt).
        float n2 = w*w + x*x + y*y + z*z;
        float t2 = 2.0f / n2;

        float xx = x*x*t2, yy = y*y*t2, zz = z*z*t2;
        float xy = x*y*t2, xz = x*z*t2, yz = y*z*t2;
        float wx = w*x*t2, wy = w*y*t2, wz = w*z*t2;

        float r00 = 1.0f - yy - zz, r01 = xy - wz,        r02 = xz + wy;
        float r10 = xy + wz,        r11 = 1.0f - xx - zz, r12 = yz - wx;
        float r20 = xz - wy,        r21 = yz + wx,        r22 = 1.0f - xx - yy;

        float s0 = fabsf(s_scale[3*t + 0]) + EPS;   // stride-3: 2 lanes/bank, free
        float s1 = fabsf(s_scale[3*t + 1]) + EPS;
        float s2 = fabsf(s_scale[3*t + 2]) + EPS;
        float a = s0*s0, b = s1*s1, c = s2*s2;

        // M = R diag(s^2) R^T, symmetric
        float m00 = r00*r00*a + r01*r01*b + r02*r02*c;
        float m01 = r00*r10*a + r01*r11*b + r02*r12*c;
        float m02 = r00*r20*a + r01*r21*b + r02*r22*c;
        float m11 = r10*r10*a + r11*r11*b + r12*r12*c;
        float m12 = r10*r20*a + r11*r21*b + r12*r22*c;
        float m22 = r20*r20*a + r21*r21*b + r22*r22*c;

        float* o = s_out + 9*t;                  // stride-9: 2 lanes/bank, free
        o[0] = m00; o[1] = m01; o[2] = m02;
        o[3] = m01; o[4] = m11; o[5] = m12;
        o[6] = m02; o[7] = m12; o[8] = m22;
    }
    __syncthreads();

    // ---- cooperative coalesced store of the out tile (576 float4 / block) ----
    {
        const int obase4 = blockIdx.x * (TILE * 9 / 4);
        const int otot4  = (9LL * n) / 4;        // 9N divisible by 4 here
        #pragma unroll
        for (int j = t; j < TILE * 9 / 4; j += TILE) {
            int go = obase4 + j;
            if (go < otot4) out4[go] = ((float4*)s_out)[j];
        }
    }
}

extern "C" void kernel_launch(void* const* d_in, const int* in_sizes, int n_in,
                              void* d_out, int out_size, void* d_ws, size_t ws_size,
                              hipStream_t stream) {
    const float4* quat   = (const float4*)d_in[0];
    const float4* scale4 = (const float4*)d_in[1];
    float4* out4 = (float4*)d_out;
    int n = in_sizes[0] / 4;   // quaternion is (N,4)

    int grid = (n + TILE - 1) / TILE;
    gaussians_cov_kernel<<<grid, TILE, 0, stream>>>(quat, scale4, out4, n);
}

// Round 4
// 214.300 us; speedup vs baseline: 1.1011x; 1.0495x over previous
//
#include <hip/hip_runtime.h>

#define EPS 1e-8f
#define TILE 512   // gaussians per block == blockDim.x

typedef float fvec4 __attribute__((ext_vector_type(4)));  // native vector: nt-builtin-compatible

__global__ __launch_bounds__(512) void gaussians_cov_kernel(
    const fvec4* __restrict__ quat,
    const fvec4* __restrict__ scale4,   // scale (N,3) viewed as fvec4 stream
    fvec4*       __restrict__ out4,     // out (N,9) viewed as fvec4 stream
    int n)
{
    __shared__ float s_scale[TILE * 3];  // 6 KB
    __shared__ float s_out[TILE * 9];    // 18 KB

    const int t    = threadIdx.x;
    const int base = blockIdx.x * TILE;

    // ---- cooperative coalesced nt-load of the scale tile (384 fvec4 / block) ----
    {
        const int sbase4 = blockIdx.x * (TILE * 3 / 4);
        const int stot4  = (3 * n) / 4;
        if (t < TILE * 3 / 4) {
            int gi = sbase4 + t;
            if (gi < stot4)
                ((fvec4*)s_scale)[t] = __builtin_nontemporal_load(&scale4[gi]);
        }
    }
    __syncthreads();

    // ---- per-thread compute ----
    const int i = base + t;
    if (i < n) {
        fvec4 q = __builtin_nontemporal_load(&quat[i]);   // coalesced 16 B/lane
        float w = q.x, x = q.y, y = q.z, z = q.w;

        // R is quadratic in normalized q: fold normalization into t2 = 2/|q|^2 (no sqrt).
        float n2 = w*w + x*x + y*y + z*z;
        float t2 = 2.0f / n2;

        float xx = x*x*t2, yy = y*y*t2, zz = z*z*t2;
        float xy = x*y*t2, xz = x*z*t2, yz = y*z*t2;
        float wx = w*x*t2, wy = w*y*t2, wz = w*z*t2;

        float r00 = 1.0f - yy - zz, r01 = xy - wz,        r02 = xz + wy;
        float r10 = xy + wz,        r11 = 1.0f - xx - zz, r12 = yz - wx;
        float r20 = xz - wy,        r21 = yz + wx,        r22 = 1.0f - xx - yy;

        float s0 = fabsf(s_scale[3*t + 0]) + EPS;   // stride-3: 2 lanes/bank, free
        float s1 = fabsf(s_scale[3*t + 1]) + EPS;
        float s2 = fabsf(s_scale[3*t + 2]) + EPS;
        float a = s0*s0, b = s1*s1, c = s2*s2;

        // M = R diag(s^2) R^T, symmetric
        float m00 = r00*r00*a + r01*r01*b + r02*r02*c;
        float m01 = r00*r10*a + r01*r11*b + r02*r12*c;
        float m02 = r00*r20*a + r01*r21*b + r02*r22*c;
        float m11 = r10*r10*a + r11*r11*b + r12*r12*c;
        float m12 = r10*r20*a + r11*r21*b + r12*r22*c;
        float m22 = r20*r20*a + r21*r21*b + r22*r22*c;

        float* o = s_out + 9*t;                  // stride-9: 2 lanes/bank, free
        o[0] = m00; o[1] = m01; o[2] = m02;
        o[3] = m01; o[4] = m11; o[5] = m12;
        o[6] = m02; o[7] = m12; o[8] = m22;
    }
    __syncthreads();

    // ---- cooperative coalesced nt-store of the out tile (1152 fvec4 / block) ----
    {
        const int obase4 = blockIdx.x * (TILE * 9 / 4);
        const long long otot4 = (9LL * n) / 4;
        #pragma unroll
        for (int j = t; j < TILE * 9 / 4; j += TILE) {
            long long go = obase4 + (long long)j;
            if (go < otot4)
                __builtin_nontemporal_store(((fvec4*)s_out)[j], &out4[go]);
        }
    }
}

extern "C" void kernel_launch(void* const* d_in, const int* in_sizes, int n_in,
                              void* d_out, int out_size, void* d_ws, size_t ws_size,
                              hipStream_t stream) {
    const fvec4* quat   = (const fvec4*)d_in[0];
    const fvec4* scale4 = (const fvec4*)d_in[1];
    fvec4* out4 = (fvec4*)d_out;
    int n = in_sizes[0] / 4;   // quaternion is (N,4)

    int grid = (n + TILE - 1) / TILE;
    gaussians_cov_kernel<<<grid, TILE, 0, stream>>>(quat, scale4, out4, n);
}